// Round 1
// baseline (1259.867 us; speedup 1.0000x reference)
//
#include <hip/hip_runtime.h>
#include <hip/hip_bf16.h>

// Problem constants (match reference)
#define D 128

// ---------------------------------------------------------------------------
// Degree count: one atomicAdd(1.0f) per edge into cnt[tgt]
// ---------------------------------------------------------------------------
__global__ void count_kernel(const int* __restrict__ etgt, float* __restrict__ cnt, int E) {
    int i = blockIdx.x * blockDim.x + threadIdx.x;
    if (i < E) atomicAdd(&cnt[etgt[i]], 1.0f);
}

// ---------------------------------------------------------------------------
// Scatter-sum of raw features: agg[tgt] += x[src]  (per (edge, d) thread)
// Consecutive lanes cover consecutive d -> coalesced loads and coalesced
// contiguous atomic RMW (256B per wave instruction).
// ---------------------------------------------------------------------------
__global__ void scatter_kernel(const float* __restrict__ x,
                               const int* __restrict__ esrc,
                               const int* __restrict__ etgt,
                               float* __restrict__ agg, int E) {
    long long idx = (long long)blockIdx.x * blockDim.x + threadIdx.x;
    const long long total = (long long)E * D;
    const long long stride = (long long)gridDim.x * blockDim.x;
    for (; idx < total; idx += stride) {
        int e = (int)(idx >> 7);
        int d = (int)(idx & (D - 1));
        int s = esrc[e];
        int t = etgt[e];
        atomicAdd(&agg[(long long)t * D + d], x[(long long)s * D + d]);
    }
}

// ---------------------------------------------------------------------------
// 128-wide GEMM: OUT[r][:] = X[r][:] @ W  (W is [128][128] row-major)
// MODE 0: plain store.
// MODE 1: OUT[r][:] = relu(OUT[r][:] + (1/max(cnt[r],1)) * (X[r][:] @ W))
// Block: 256 threads, 64 rows/block. LDS: W half-tile [64][128] + X tile [64][64].
// Thread (c32 = tid&31, rg = tid>>5) computes cols 4*c32..+3 for rows rg+8*i.
// ---------------------------------------------------------------------------
template <int MODE>
__global__ __launch_bounds__(256) void gemm128_k(const float* __restrict__ X,
                                                 const float* __restrict__ W,
                                                 float* __restrict__ OUT, int nrows,
                                                 const float* __restrict__ cnt) {
    __shared__ float sW[64][128];
    __shared__ float sX[64][64];
    const int tid = threadIdx.x;
    const int c32 = tid & 31;
    const int rg  = tid >> 5;
    const int base = blockIdx.x * 64;

    float acc[8][4];
#pragma unroll
    for (int i = 0; i < 8; i++)
#pragma unroll
        for (int j = 0; j < 4; j++) acc[i][j] = 0.f;

    for (int kk = 0; kk < 128; kk += 64) {
        __syncthreads();
        // W[kk..kk+63][0..127] -> sW : 2048 float4, 8 per thread
#pragma unroll
        for (int l = 0; l < 8; l++) {
            int fi = l * 256 + tid;       // float4 index
            int k = fi >> 5;              // 32 float4 per row of 128
            int c = (fi & 31) * 4;
            *(float4*)&sW[k][c] = *(const float4*)&W[(kk + k) * D + c];
        }
        // X[base..base+63][kk..kk+63] -> sX : 1024 float4, 4 per thread
#pragma unroll
        for (int l = 0; l < 4; l++) {
            int fi = l * 256 + tid;
            int r = fi >> 4;              // 16 float4 per row of 64
            int c = (fi & 15) * 4;
            int row = base + r;
            if (row >= nrows) row = nrows - 1;
            *(float4*)&sX[r][c] = *(const float4*)&X[(long long)row * D + kk + c];
        }
        __syncthreads();
#pragma unroll 16
        for (int k = 0; k < 64; k++) {
            float4 wv = *(const float4*)&sW[k][c32 * 4];
#pragma unroll
            for (int i = 0; i < 8; i++) {
                float xv = sX[rg + 8 * i][k];
                acc[i][0] += xv * wv.x;
                acc[i][1] += xv * wv.y;
                acc[i][2] += xv * wv.z;
                acc[i][3] += xv * wv.w;
            }
        }
    }

#pragma unroll
    for (int i = 0; i < 8; i++) {
        int row = base + rg + 8 * i;
        if (row < nrows) {
            float* p = &OUT[(long long)row * D + c32 * 4];
            float4 v = {acc[i][0], acc[i][1], acc[i][2], acc[i][3]};
            if (MODE == 1) {
                float scale = 1.0f / fmaxf(cnt[row], 1.0f);
                float4 old = *(const float4*)p;
                v.x = fmaxf(old.x + scale * v.x, 0.f);
                v.y = fmaxf(old.y + scale * v.y, 0.f);
                v.z = fmaxf(old.z + scale * v.z, 0.f);
                v.w = fmaxf(old.w + scale * v.w, 0.f);
            }
            *(float4*)p = v;
        }
    }
}

extern "C" void kernel_launch(void* const* d_in, const int* in_sizes, int n_in,
                              void* d_out, int out_size, void* d_ws, size_t ws_size,
                              hipStream_t stream) {
    const float* x_user    = (const float*)d_in[0];
    const float* x_poi     = (const float*)d_in[1];
    const float* W_u2p_src = (const float*)d_in[2];
    const float* W_u2p_tgt = (const float*)d_in[3];
    const float* W_p2u_src = (const float*)d_in[4];
    const float* W_p2u_tgt = (const float*)d_in[5];
    const int* e_u2p_src   = (const int*)d_in[6];
    const int* e_u2p_tgt   = (const int*)d_in[7];
    const int* e_p2u_src   = (const int*)d_in[8];
    const int* e_p2u_tgt   = (const int*)d_in[9];

    const int n_user = in_sizes[0] / D;   // 100000
    const int n_poi  = in_sizes[1] / D;   // 50000
    const int E1 = in_sizes[6];           // u2p edges
    const int E2 = in_sizes[8];           // p2u edges

    float* out = (float*)d_out;
    float* out_user = out;                       // rows [0, n_user)
    float* out_poi  = out + (long long)n_user * D;

    // Workspace layout (floats)
    float* ws = (float*)d_ws;
    float* agg_user = ws;                                   // n_user*D
    float* agg_poi  = agg_user + (long long)n_user * D;     // n_poi*D
    float* cnt_user = agg_poi + (long long)n_poi * D;       // n_user
    float* cnt_poi  = cnt_user + n_user;                    // n_poi

    // 1) zero accumulators + counts
    hipMemsetAsync(agg_user, 0, sizeof(float) * ((size_t)n_user * D + (size_t)n_poi * D
                                                 + n_user + n_poi), stream);

    // 2) degree counts
    {
        int thr = 256;
        count_kernel<<<(E1 + thr - 1) / thr, thr, 0, stream>>>(e_u2p_tgt, cnt_poi, E1);
        count_kernel<<<(E2 + thr - 1) / thr, thr, 0, stream>>>(e_p2u_tgt, cnt_user, E2);
    }

    // 3) raw-feature scatter-sum
    {
        int thr = 256;
        int blocks = 8192;
        scatter_kernel<<<blocks, thr, 0, stream>>>(x_user, e_u2p_src, e_u2p_tgt, agg_poi, E1);
        scatter_kernel<<<blocks, thr, 0, stream>>>(x_poi,  e_p2u_src, e_p2u_tgt, agg_user, E2);
    }

    // 4) GEMM1: out = x @ W_tgt
    {
        int bu = (n_user + 63) / 64, bp = (n_poi + 63) / 64;
        gemm128_k<0><<<bu, 256, 0, stream>>>(x_user, W_p2u_tgt, out_user, n_user, nullptr);
        gemm128_k<0><<<bp, 256, 0, stream>>>(x_poi,  W_u2p_tgt, out_poi,  n_poi,  nullptr);
    }

    // 5) GEMM2 fused: out = relu(out + (1/max(cnt,1)) * (agg @ W_src))
    {
        int bu = (n_user + 63) / 64, bp = (n_poi + 63) / 64;
        gemm128_k<1><<<bu, 256, 0, stream>>>(agg_user, W_p2u_src, out_user, n_user, cnt_user);
        gemm128_k<1><<<bp, 256, 0, stream>>>(agg_poi,  W_u2p_src, out_poi,  n_poi,  cnt_poi);
    }
}

// Round 2
// 672.216 us; speedup vs baseline: 1.8742x; 1.8742x over previous
//
#include <hip/hip_runtime.h>
#include <hip/hip_bf16.h>

#define D 128

// ---------------------------------------------------------------------------
// 64-lane wave inclusive scan (int)
// ---------------------------------------------------------------------------
__device__ __forceinline__ int wave_incl_scan(int v) {
    int lane = threadIdx.x & 63;
#pragma unroll
    for (int off = 1; off < 64; off <<= 1) {
        int n = __shfl_up(v, off, 64);
        if (lane >= off) v += n;
    }
    return v;
}

// ---------------------------------------------------------------------------
// Degree count: int atomicAdd per edge (cheap: 1M 4B atomics)
// ---------------------------------------------------------------------------
__global__ void count_k(const int* __restrict__ etgt, int* __restrict__ deg, int E) {
    int i = blockIdx.x * blockDim.x + threadIdx.x;
    if (i < E) atomicAdd(&deg[etgt[i]], 1);
}

// ---------------------------------------------------------------------------
// Scan stage 1: per-block (1024 elems) total -> bsums[b]
// ---------------------------------------------------------------------------
__global__ __launch_bounds__(256) void scan_sums_k(const int* __restrict__ deg, int n,
                                                   int* __restrict__ bsums) {
    __shared__ int wsum[4];
    int base = blockIdx.x * 1024 + threadIdx.x * 4;
    int s = 0;
#pragma unroll
    for (int l = 0; l < 4; l++) {
        int i = base + l;
        s += (i < n) ? deg[i] : 0;
    }
    int isc = wave_incl_scan(s);
    int lane = threadIdx.x & 63, wid = threadIdx.x >> 6;
    if (lane == 63) wsum[wid] = isc;
    __syncthreads();
    if (threadIdx.x == 0) bsums[blockIdx.x] = wsum[0] + wsum[1] + wsum[2] + wsum[3];
}

// ---------------------------------------------------------------------------
// Scan stage 2: exclusive-scan the block sums in place. Wave 0 -> user array,
// wave 1 -> poi array. nb <= 128 per array (n <= 128K).
// ---------------------------------------------------------------------------
__global__ __launch_bounds__(128) void scan_offsets_k(int* __restrict__ bs_u, int nbu,
                                                      int* __restrict__ bs_p, int nbp) {
    int lane = threadIdx.x & 63;
    int w = threadIdx.x >> 6;
    int* bs = w ? bs_p : bs_u;
    int nb = w ? nbp : nbu;
    int carry = 0;
    for (int r = 0; r * 64 < nb; r++) {
        int i = r * 64 + lane;
        int v = (i < nb) ? bs[i] : 0;
        int isc = wave_incl_scan(v);
        if (i < nb) bs[i] = isc - v + carry;
        carry += __shfl(isc, 63, 64);
    }
}

// ---------------------------------------------------------------------------
// Scan stage 3: per-block local exclusive scan + block offset -> start, cursor
// ---------------------------------------------------------------------------
__global__ __launch_bounds__(256) void scan_apply_k(const int* __restrict__ deg, int n,
                                                    const int* __restrict__ bsums,
                                                    int* __restrict__ start,
                                                    int* __restrict__ cursor) {
    __shared__ int wsum[4];
    int base = blockIdx.x * 1024 + threadIdx.x * 4;
    int v[4]; int s = 0;
#pragma unroll
    for (int l = 0; l < 4; l++) { int i = base + l; v[l] = (i < n) ? deg[i] : 0; s += v[l]; }
    int isc = wave_incl_scan(s);
    int lane = threadIdx.x & 63, wid = threadIdx.x >> 6;
    if (lane == 63) wsum[wid] = isc;
    __syncthreads();
    int woff = 0;
#pragma unroll
    for (int k = 0; k < 4; k++) if (k < wid) woff += wsum[k];
    int run = isc - s + woff + bsums[blockIdx.x];
#pragma unroll
    for (int l = 0; l < 4; l++) {
        int i = base + l;
        if (i < n) { start[i] = run; cursor[i] = run; run += v[l]; }
    }
}

// ---------------------------------------------------------------------------
// Permute: ticket into CSR slot, store the SOURCE node id directly.
// ---------------------------------------------------------------------------
__global__ void permute_k(const int* __restrict__ esrc, const int* __restrict__ etgt,
                          int* __restrict__ cursor, int* __restrict__ perm, int E) {
    int i = blockIdx.x * blockDim.x + threadIdx.x;
    if (i < E) {
        int t = etgt[i];
        int pos = atomicAdd(&cursor[t], 1);
        perm[pos] = esrc[i];
    }
}

// ---------------------------------------------------------------------------
// Gather-side segment sum: one wave per target. Lane holds float2 (128 cols /
// 64 lanes). Row reads are 512B coalesced; x is L2/L3 resident. No atomics.
// Writes the raw sum into agg (= the output buffer rows, reused as scratch).
// ---------------------------------------------------------------------------
__global__ __launch_bounds__(256) void gather_k(const float* __restrict__ x,
                                                const int* __restrict__ perm,
                                                const int* __restrict__ start,
                                                const int* __restrict__ deg,
                                                float* __restrict__ agg, int nT) {
    int gw = (blockIdx.x * 256 + threadIdx.x) >> 6;
    int lane = threadIdx.x & 63;
    int nW = (gridDim.x * 256) >> 6;
    for (int t = gw; t < nT; t += nW) {
        int s0 = start[t], dg = deg[t];
        float ax = 0.f, ay = 0.f;
        int j = 0;
        for (; j + 4 <= dg; j += 4) {
            int sa = perm[s0 + j], sb = perm[s0 + j + 1];
            int sc = perm[s0 + j + 2], sd = perm[s0 + j + 3];
            float2 va = *(const float2*)&x[sa * D + lane * 2];
            float2 vb = *(const float2*)&x[sb * D + lane * 2];
            float2 vc = *(const float2*)&x[sc * D + lane * 2];
            float2 vd = *(const float2*)&x[sd * D + lane * 2];
            ax += (va.x + vb.x) + (vc.x + vd.x);
            ay += (va.y + vb.y) + (vc.y + vd.y);
        }
        for (; j < dg; j++) {
            int s = perm[s0 + j];
            float2 v = *(const float2*)&x[s * D + lane * 2];
            ax += v.x; ay += v.y;
        }
        float2 o = {ax, ay};
        *(float2*)&agg[(long long)t * D + lane * 2] = o;
    }
}

// ---------------------------------------------------------------------------
// Fused dual-GEMM epilogue:
//   OUT[r] = relu( X[r]@Wt + (1/max(deg[r],1)) * OUT[r]@Ws )
// OUT initially holds the raw gathered sums (agg). Each block owns 64 rows:
// it reads its own agg rows (pre-scaled at LDS load) before overwriting them.
// ---------------------------------------------------------------------------
__global__ __launch_bounds__(256) void fused_gemm_k(const float* __restrict__ X,
                                                    const float* __restrict__ Wt,
                                                    const float* __restrict__ Ws,
                                                    const int* __restrict__ deg,
                                                    float* __restrict__ OUT, int nrows) {
    __shared__ float sW[64][128];
    __shared__ float sX[64][64];
    const int tid = threadIdx.x;
    const int c32 = tid & 31;
    const int rg  = tid >> 5;
    const int base = blockIdx.x * 64;

    float acc[8][4];
#pragma unroll
    for (int i = 0; i < 8; i++)
#pragma unroll
        for (int j = 0; j < 4; j++) acc[i][j] = 0.f;

    for (int pass = 0; pass < 2; pass++) {
        const float* src = pass ? OUT : X;
        const float* W   = pass ? Ws  : Wt;
        for (int kk = 0; kk < 128; kk += 64) {
            __syncthreads();
#pragma unroll
            for (int l = 0; l < 8; l++) {
                int fi = l * 256 + tid;
                int k = fi >> 5;
                int c = (fi & 31) * 4;
                *(float4*)&sW[k][c] = *(const float4*)&W[(kk + k) * D + c];
            }
#pragma unroll
            for (int l = 0; l < 4; l++) {
                int fi = l * 256 + tid;
                int r = fi >> 4;
                int c = (fi & 15) * 4;
                int row = base + r;
                if (row >= nrows) row = nrows - 1;
                float4 v = *(const float4*)&src[(long long)row * D + kk + c];
                if (pass) {
                    float scl = 1.0f / fmaxf((float)deg[row], 1.0f);
                    v.x *= scl; v.y *= scl; v.z *= scl; v.w *= scl;
                }
                *(float4*)&sX[r][c] = v;
            }
            __syncthreads();
#pragma unroll 16
            for (int k = 0; k < 64; k++) {
                float4 wv = *(const float4*)&sW[k][c32 * 4];
#pragma unroll
                for (int i = 0; i < 8; i++) {
                    float xv = sX[rg + 8 * i][k];
                    acc[i][0] += xv * wv.x;
                    acc[i][1] += xv * wv.y;
                    acc[i][2] += xv * wv.z;
                    acc[i][3] += xv * wv.w;
                }
            }
        }
    }

#pragma unroll
    for (int i = 0; i < 8; i++) {
        int row = base + rg + 8 * i;
        if (row < nrows) {
            float4 v = {fmaxf(acc[i][0], 0.f), fmaxf(acc[i][1], 0.f),
                        fmaxf(acc[i][2], 0.f), fmaxf(acc[i][3], 0.f)};
            *(float4*)&OUT[(long long)row * D + c32 * 4] = v;
        }
    }
}

extern "C" void kernel_launch(void* const* d_in, const int* in_sizes, int n_in,
                              void* d_out, int out_size, void* d_ws, size_t ws_size,
                              hipStream_t stream) {
    const float* x_user    = (const float*)d_in[0];
    const float* x_poi     = (const float*)d_in[1];
    const float* W_u2p_src = (const float*)d_in[2];
    const float* W_u2p_tgt = (const float*)d_in[3];
    const float* W_p2u_src = (const float*)d_in[4];
    const float* W_p2u_tgt = (const float*)d_in[5];
    const int* e_u2p_src   = (const int*)d_in[6];
    const int* e_u2p_tgt   = (const int*)d_in[7];
    const int* e_p2u_src   = (const int*)d_in[8];
    const int* e_p2u_tgt   = (const int*)d_in[9];

    const int n_user = in_sizes[0] / D;   // 100000
    const int n_poi  = in_sizes[1] / D;   // 50000
    const int E1 = in_sizes[6];           // u2p edges (targets = poi)
    const int E2 = in_sizes[8];           // p2u edges (targets = user)

    float* out = (float*)d_out;
    float* out_user = out;
    float* out_poi  = out + (long long)n_user * D;

    const int nb_u = (n_user + 1023) / 1024;
    const int nb_p = (n_poi + 1023) / 1024;

    // Workspace (ints): ~10 MB total
    int* wsI = (int*)d_ws;
    int* deg_user   = wsI;
    int* deg_poi    = deg_user + n_user;
    int* start_user = deg_poi + n_poi;
    int* start_poi  = start_user + n_user;
    int* cur_user   = start_poi + n_poi;
    int* cur_poi    = cur_user + n_user;
    int* bs_user    = cur_poi + n_poi;
    int* bs_poi     = bs_user + nb_u;
    int* perm_user  = bs_poi + nb_p;      // E2 entries (poi src ids)
    int* perm_poi   = perm_user + E2;     // E1 entries (user src ids)

    // 1) zero degrees
    hipMemsetAsync(deg_user, 0, sizeof(int) * (size_t)(n_user + n_poi), stream);

    // 2) degree counts
    count_k<<<(E1 + 255) / 256, 256, 0, stream>>>(e_u2p_tgt, deg_poi, E1);
    count_k<<<(E2 + 255) / 256, 256, 0, stream>>>(e_p2u_tgt, deg_user, E2);

    // 3) exclusive scan -> start/cursor
    scan_sums_k<<<nb_u, 256, 0, stream>>>(deg_user, n_user, bs_user);
    scan_sums_k<<<nb_p, 256, 0, stream>>>(deg_poi, n_poi, bs_poi);
    scan_offsets_k<<<1, 128, 0, stream>>>(bs_user, nb_u, bs_poi, nb_p);
    scan_apply_k<<<nb_u, 256, 0, stream>>>(deg_user, n_user, bs_user, start_user, cur_user);
    scan_apply_k<<<nb_p, 256, 0, stream>>>(deg_poi, n_poi, bs_poi, start_poi, cur_poi);

    // 4) CSR permute (store src node ids)
    permute_k<<<(E1 + 255) / 256, 256, 0, stream>>>(e_u2p_src, e_u2p_tgt, cur_poi, perm_poi, E1);
    permute_k<<<(E2 + 255) / 256, 256, 0, stream>>>(e_p2u_src, e_p2u_tgt, cur_user, perm_user, E2);

    // 5) gather-side segment sums, written straight into d_out rows
    gather_k<<<(n_user + 3) / 4, 256, 0, stream>>>(x_poi, perm_user, start_user, deg_user,
                                                   out_user, n_user);
    gather_k<<<(n_poi + 3) / 4, 256, 0, stream>>>(x_user, perm_poi, start_poi, deg_poi,
                                                  out_poi, n_poi);

    // 6) fused dual GEMM + mean-scale + relu, in place on d_out
    fused_gemm_k<<<(n_user + 63) / 64, 256, 0, stream>>>(x_user, W_p2u_tgt, W_p2u_src,
                                                         deg_user, out_user, n_user);
    fused_gemm_k<<<(n_poi + 63) / 64, 256, 0, stream>>>(x_poi, W_u2p_tgt, W_u2p_src,
                                                        deg_poi, out_poi, n_poi);
}

// Round 3
// 544.288 us; speedup vs baseline: 2.3147x; 1.2350x over previous
//
#include <hip/hip_runtime.h>
#include <hip/hip_bf16.h>

#define D 128

typedef __attribute__((ext_vector_type(8))) short bf16x8;  // 8 bf16 = 4 VGPRs
typedef __attribute__((ext_vector_type(4))) float f32x4;

__device__ __forceinline__ ushort f2bf(float f) {
    uint u = __float_as_uint(f);
    u += 0x7fffu + ((u >> 16) & 1u);   // RNE
    return (ushort)(u >> 16);
}

// ---------------------------------------------------------------------------
// f32 -> bf16 cast (vectorized: float4 in, ushort4 out)
// ---------------------------------------------------------------------------
__global__ __launch_bounds__(256) void cast_x_k(const float* __restrict__ x,
                                                ushort* __restrict__ xb, long long n4) {
    long long i = (long long)blockIdx.x * 256 + threadIdx.x;
    long long stride = (long long)gridDim.x * 256;
    for (; i < n4; i += stride) {
        float4 v = ((const float4*)x)[i];
        ushort4 o = {f2bf(v.x), f2bf(v.y), f2bf(v.z), f2bf(v.w)};
        ((ushort4*)xb)[i] = o;
    }
}

// ---------------------------------------------------------------------------
// Pack 4 weight matrices [128][128] f32 into MFMA B-fragment order (bf16):
// P[w][(kk*8+n0)*64 + lane][j] = bf16( W[kk*32 + (lane>>4)*8 + j][n0*16 + (lane&15)] )
// ---------------------------------------------------------------------------
__global__ void pack_w_k(const float* __restrict__ W0, const float* __restrict__ W1,
                         const float* __restrict__ W2, const float* __restrict__ W3,
                         ushort* __restrict__ P) {
    int t = blockIdx.x * 256 + threadIdx.x;
    if (t >= 4 * 2048) return;
    int w = t >> 11, r = t & 2047;
    int lane = r & 63, fi = r >> 6;
    int kk = fi >> 3, n0 = fi & 7;
    const float* W = (w == 0) ? W0 : (w == 1) ? W1 : (w == 2) ? W2 : W3;
    int col = n0 * 16 + (lane & 15);
    int kb = kk * 32 + (lane >> 4) * 8;
    bf16x8 v;
#pragma unroll
    for (int j = 0; j < 8; j++) v[j] = (short)f2bf(W[(kb + j) * D + col]);
    *(bf16x8*)&P[(long long)t * 8] = v;
}

// ---------------------------------------------------------------------------
// 64-lane wave inclusive scan (int)
// ---------------------------------------------------------------------------
__device__ __forceinline__ int wave_incl_scan(int v) {
    int lane = threadIdx.x & 63;
#pragma unroll
    for (int off = 1; off < 64; off <<= 1) {
        int n = __shfl_up(v, off, 64);
        if (lane >= off) v += n;
    }
    return v;
}

__global__ void count_k(const int* __restrict__ etgt, int* __restrict__ deg, int E) {
    int i = blockIdx.x * blockDim.x + threadIdx.x;
    if (i < E) atomicAdd(&deg[etgt[i]], 1);
}

__global__ __launch_bounds__(256) void scan_sums_k(const int* __restrict__ deg, int n,
                                                   int* __restrict__ bsums) {
    __shared__ int wsum[4];
    int base = blockIdx.x * 1024 + threadIdx.x * 4;
    int s = 0;
#pragma unroll
    for (int l = 0; l < 4; l++) {
        int i = base + l;
        s += (i < n) ? deg[i] : 0;
    }
    int isc = wave_incl_scan(s);
    int lane = threadIdx.x & 63, wid = threadIdx.x >> 6;
    if (lane == 63) wsum[wid] = isc;
    __syncthreads();
    if (threadIdx.x == 0) bsums[blockIdx.x] = wsum[0] + wsum[1] + wsum[2] + wsum[3];
}

__global__ __launch_bounds__(128) void scan_offsets_k(int* __restrict__ bs_u, int nbu,
                                                      int* __restrict__ bs_p, int nbp) {
    int lane = threadIdx.x & 63;
    int w = threadIdx.x >> 6;
    int* bs = w ? bs_p : bs_u;
    int nb = w ? nbp : nbu;
    int carry = 0;
    for (int r = 0; r * 64 < nb; r++) {
        int i = r * 64 + lane;
        int v = (i < nb) ? bs[i] : 0;
        int isc = wave_incl_scan(v);
        if (i < nb) bs[i] = isc - v + carry;
        carry += __shfl(isc, 63, 64);
    }
}

__global__ __launch_bounds__(256) void scan_apply_k(const int* __restrict__ deg, int n,
                                                    const int* __restrict__ bsums,
                                                    int* __restrict__ start,
                                                    int* __restrict__ cursor) {
    __shared__ int wsum[4];
    int base = blockIdx.x * 1024 + threadIdx.x * 4;
    int v[4]; int s = 0;
#pragma unroll
    for (int l = 0; l < 4; l++) { int i = base + l; v[l] = (i < n) ? deg[i] : 0; s += v[l]; }
    int isc = wave_incl_scan(s);
    int lane = threadIdx.x & 63, wid = threadIdx.x >> 6;
    if (lane == 63) wsum[wid] = isc;
    __syncthreads();
    int woff = 0;
#pragma unroll
    for (int k = 0; k < 4; k++) if (k < wid) woff += wsum[k];
    int run = isc - s + woff + bsums[blockIdx.x];
#pragma unroll
    for (int l = 0; l < 4; l++) {
        int i = base + l;
        if (i < n) { start[i] = run; cursor[i] = run; run += v[l]; }
    }
}

__global__ void permute_k(const int* __restrict__ esrc, const int* __restrict__ etgt,
                          int* __restrict__ cursor, int* __restrict__ perm, int E) {
    int i = blockIdx.x * blockDim.x + threadIdx.x;
    if (i < E) {
        int t = etgt[i];
        int pos = atomicAdd(&cursor[t], 1);
        perm[pos] = esrc[i];
    }
}

// ---------------------------------------------------------------------------
// Gather-side segment MEAN in bf16: one wave per target, lane holds 2 cols
// (bf16x2 = 4B/lane, 256B per row read). Accumulate f32, scale by 1/max(deg,1),
// write bf16x2. No atomics.
// ---------------------------------------------------------------------------
__global__ __launch_bounds__(256) void gather_k(const ushort* __restrict__ xb,
                                                const int* __restrict__ perm,
                                                const int* __restrict__ start,
                                                const int* __restrict__ deg,
                                                ushort* __restrict__ aggb, int nT) {
    int gw = (blockIdx.x * 256 + threadIdx.x) >> 6;
    int lane = threadIdx.x & 63;
    if (gw >= nT) return;
    const uint* x2 = (const uint*)xb;
    int s0 = start[gw], dg = deg[gw];
    float ax = 0.f, ay = 0.f;
    int j = 0;
    for (; j + 4 <= dg; j += 4) {
        int sa = perm[s0 + j], sb = perm[s0 + j + 1];
        int sc = perm[s0 + j + 2], sd = perm[s0 + j + 3];
        uint va = x2[sa * 64 + lane], vb = x2[sb * 64 + lane];
        uint vc = x2[sc * 64 + lane], vd = x2[sd * 64 + lane];
        ax += (__uint_as_float(va << 16) + __uint_as_float(vb << 16)) +
              (__uint_as_float(vc << 16) + __uint_as_float(vd << 16));
        ay += (__uint_as_float(va & 0xffff0000u) + __uint_as_float(vb & 0xffff0000u)) +
              (__uint_as_float(vc & 0xffff0000u) + __uint_as_float(vd & 0xffff0000u));
    }
    for (; j < dg; j++) {
        int s = perm[s0 + j];
        uint v = x2[s * 64 + lane];
        ax += __uint_as_float(v << 16);
        ay += __uint_as_float(v & 0xffff0000u);
    }
    float scl = 1.0f / fmaxf((float)dg, 1.0f);
    uint o = ((uint)f2bf(ay * scl) << 16) | (uint)f2bf(ax * scl);
    ((uint*)aggb)[(long long)gw * 64 + lane] = o;
}

// ---------------------------------------------------------------------------
// Fused dual-GEMM via MFMA, no LDS:
//   OUT[r] = relu( Xb[r]@Wt + Aggb[r]@Ws )   (agg already holds the mean)
// Block = 256 thr = 4 waves; 128 rows/block; wave w owns rows base+w*32.
// A-frags from global (16B/lane contiguous); B-frags from pre-packed weights.
// ---------------------------------------------------------------------------
__global__ __launch_bounds__(256) void mfma_gemm_k(const ushort* __restrict__ Xb,
                                                   const ushort* __restrict__ Aggb,
                                                   const ushort* __restrict__ WtP,
                                                   const ushort* __restrict__ WsP,
                                                   float* __restrict__ OUT, int nrows) {
    const int tid = threadIdx.x;
    const int lane = tid & 63;
    const int wv = tid >> 6;
    const int waveRow = blockIdx.x * 128 + wv * 32;
    const int l15 = lane & 15, lhi = lane >> 4;

    f32x4 acc[2][8];
#pragma unroll
    for (int m = 0; m < 2; m++)
#pragma unroll
        for (int n = 0; n < 8; n++) acc[m][n] = (f32x4){0.f, 0.f, 0.f, 0.f};

#pragma unroll
    for (int p = 0; p < 2; p++) {
        const ushort* Xp = p ? Aggb : Xb;
        const ushort* Wp = p ? WsP : WtP;
#pragma unroll
        for (int kk = 0; kk < 4; kk++) {
            bf16x8 a[2];
#pragma unroll
            for (int m = 0; m < 2; m++) {
                int r = waveRow + m * 16 + l15;
                if (r > nrows - 1) r = nrows - 1;
                a[m] = *(const bf16x8*)&Xp[(long long)r * D + kk * 32 + lhi * 8];
            }
#pragma unroll
            for (int n = 0; n < 8; n++) {
                bf16x8 b = *(const bf16x8*)&Wp[(long long)((kk * 8 + n) * 64 + lane) * 8];
#pragma unroll
                for (int m = 0; m < 2; m++)
                    acc[m][n] = __builtin_amdgcn_mfma_f32_16x16x32_bf16(a[m], b, acc[m][n], 0, 0, 0);
            }
        }
    }

#pragma unroll
    for (int m = 0; m < 2; m++)
#pragma unroll
        for (int n = 0; n < 8; n++)
#pragma unroll
            for (int ri = 0; ri < 4; ri++) {
                int r = waveRow + m * 16 + lhi * 4 + ri;
                if (r < nrows)
                    OUT[(long long)r * D + n * 16 + l15] = fmaxf(acc[m][n][ri], 0.f);
            }
}

extern "C" void kernel_launch(void* const* d_in, const int* in_sizes, int n_in,
                              void* d_out, int out_size, void* d_ws, size_t ws_size,
                              hipStream_t stream) {
    const float* x_user    = (const float*)d_in[0];
    const float* x_poi     = (const float*)d_in[1];
    const float* W_u2p_src = (const float*)d_in[2];
    const float* W_u2p_tgt = (const float*)d_in[3];
    const float* W_p2u_src = (const float*)d_in[4];
    const float* W_p2u_tgt = (const float*)d_in[5];
    const int* e_u2p_src   = (const int*)d_in[6];
    const int* e_u2p_tgt   = (const int*)d_in[7];
    const int* e_p2u_src   = (const int*)d_in[8];
    const int* e_p2u_tgt   = (const int*)d_in[9];

    const int n_user = in_sizes[0] / D;   // 100000
    const int n_poi  = in_sizes[1] / D;   // 50000
    const int E1 = in_sizes[6];           // u2p edges (targets = poi, srcs = user)
    const int E2 = in_sizes[8];           // p2u edges (targets = user, srcs = poi)
    const int Emax = (E1 > E2) ? E1 : E2;

    float* out = (float*)d_out;
    float* out_user = out;
    float* out_poi  = out + (long long)n_user * D;

    const int nb_u = (n_user + 1023) / 1024;
    const int nb_p = (n_poi + 1023) / 1024;
    const int nmax = (n_user > n_poi) ? n_user : n_poi;

    // ---- workspace layout (bytes) ----
    char* w = (char*)d_ws;
    ushort* xb_user = (ushort*)w;                 w += (size_t)n_user * D * 2;
    ushort* xb_poi  = (ushort*)w;                 w += (size_t)n_poi  * D * 2;
    ushort* aggb    = (ushort*)w;                 w += (size_t)nmax   * D * 2;  // shared
    ushort* Wpack   = (ushort*)w;                 w += (size_t)4 * 2048 * 8 * 2;
    int* perm       = (int*)w;                    w += (size_t)Emax * 4;        // shared
    int* deg_user   = (int*)w;                    w += (size_t)n_user * 4;
    int* deg_poi    = (int*)w;                    w += (size_t)n_poi * 4;
    int* start_user = (int*)w;                    w += (size_t)n_user * 4;
    int* start_poi  = (int*)w;                    w += (size_t)n_poi * 4;
    int* cur_user   = (int*)w;                    w += (size_t)n_user * 4;
    int* cur_poi    = (int*)w;                    w += (size_t)n_poi * 4;
    int* bs_user    = (int*)w;                    w += (size_t)nb_u * 4;
    int* bs_poi     = (int*)w;                    w += (size_t)nb_p * 4;

    // packed weight slices: w0=p2u_tgt w1=p2u_src w2=u2p_tgt w3=u2p_src
    ushort* WtP_user = Wpack + 0 * 2048 * 8;
    ushort* WsP_user = Wpack + 1 * 2048 * 8;
    ushort* WtP_poi  = Wpack + 2 * 2048 * 8;
    ushort* WsP_poi  = Wpack + 3 * 2048 * 8;

    // 1) casts + weight pack
    {
        long long n4u = (long long)n_user * D / 4;
        long long n4p = (long long)n_poi * D / 4;
        cast_x_k<<<(int)((n4u + 255) / 256), 256, 0, stream>>>(x_user, xb_user, n4u);
        cast_x_k<<<(int)((n4p + 255) / 256), 256, 0, stream>>>(x_poi, xb_poi, n4p);
        pack_w_k<<<32, 256, 0, stream>>>(W_p2u_tgt, W_p2u_src, W_u2p_tgt, W_u2p_src, Wpack);
    }

    // 2) degrees
    hipMemsetAsync(deg_user, 0, sizeof(int) * (size_t)(n_user + n_poi), stream);
    count_k<<<(E1 + 255) / 256, 256, 0, stream>>>(e_u2p_tgt, deg_poi, E1);
    count_k<<<(E2 + 255) / 256, 256, 0, stream>>>(e_p2u_tgt, deg_user, E2);

    // 3) exclusive scans -> start/cursor
    scan_sums_k<<<nb_u, 256, 0, stream>>>(deg_user, n_user, bs_user);
    scan_sums_k<<<nb_p, 256, 0, stream>>>(deg_poi, n_poi, bs_poi);
    scan_offsets_k<<<1, 128, 0, stream>>>(bs_user, nb_u, bs_poi, nb_p);
    scan_apply_k<<<nb_u, 256, 0, stream>>>(deg_user, n_user, bs_user, start_user, cur_user);
    scan_apply_k<<<nb_p, 256, 0, stream>>>(deg_poi, n_poi, bs_poi, start_poi, cur_poi);

    // 4) USER targets: permute -> gather(mean, bf16) -> fused MFMA GEMM
    permute_k<<<(E2 + 255) / 256, 256, 0, stream>>>(e_p2u_src, e_p2u_tgt, cur_user, perm, E2);
    gather_k<<<(n_user + 3) / 4, 256, 0, stream>>>(xb_poi, perm, start_user, deg_user,
                                                   aggb, n_user);
    mfma_gemm_k<<<(n_user + 127) / 128, 256, 0, stream>>>(xb_user, aggb, WtP_user, WsP_user,
                                                          out_user, n_user);

    // 5) POI targets: permute -> gather -> fused MFMA GEMM (reuses perm/aggb)
    permute_k<<<(E1 + 255) / 256, 256, 0, stream>>>(e_u2p_src, e_u2p_tgt, cur_poi, perm, E1);
    gather_k<<<(n_poi + 3) / 4, 256, 0, stream>>>(xb_user, perm, start_poi, deg_poi,
                                                  aggb, n_poi);
    mfma_gemm_k<<<(n_poi + 127) / 128, 256, 0, stream>>>(xb_poi, aggb, WtP_poi, WsP_poi,
                                                         out_poi, n_poi);
}

// Round 4
// 442.356 us; speedup vs baseline: 2.8481x; 1.2304x over previous
//
#include <hip/hip_runtime.h>
#include <hip/hip_bf16.h>

#define D 128

typedef __attribute__((ext_vector_type(8))) short bf16x8;  // 8 bf16 = 4 VGPRs
typedef __attribute__((ext_vector_type(4))) float f32x4;

__device__ __forceinline__ ushort f2bf(float f) {
    uint u = __float_as_uint(f);
    u += 0x7fffu + ((u >> 16) & 1u);   // RNE
    return (ushort)(u >> 16);
}

__device__ __forceinline__ int wave_incl_scan(int v) {
    int lane = threadIdx.x & 63;
#pragma unroll
    for (int off = 1; off < 64; off <<= 1) {
        int n = __shfl_up(v, off, 64);
        if (lane >= off) v += n;
    }
    return v;
}

// ---------------------------------------------------------------------------
// K1: fused cast (f32->bf16, both node sets) + degree count w/ ticket capture
// ---------------------------------------------------------------------------
__global__ __launch_bounds__(256) void prep_k(
        const float* __restrict__ xu, ushort* __restrict__ xbu, long long n4u,
        const float* __restrict__ xp, ushort* __restrict__ xbp, long long n4p,
        const int* __restrict__ t1, int* __restrict__ tick1, int* __restrict__ degp, int E1,
        const int* __restrict__ t2, int* __restrict__ tick2, int* __restrict__ degu, int E2) {
    long long g = (long long)blockIdx.x * 256 + threadIdx.x;
    long long gs = (long long)gridDim.x * 256;
    for (long long i = g; i < n4u; i += gs) {
        float4 v = ((const float4*)xu)[i];
        ushort4 o = {f2bf(v.x), f2bf(v.y), f2bf(v.z), f2bf(v.w)};
        ((ushort4*)xbu)[i] = o;
    }
    for (long long i = g; i < n4p; i += gs) {
        float4 v = ((const float4*)xp)[i];
        ushort4 o = {f2bf(v.x), f2bf(v.y), f2bf(v.z), f2bf(v.w)};
        ((ushort4*)xbp)[i] = o;
    }
    for (long long i = g; i < E1; i += gs) tick1[i] = atomicAdd(&degp[t1[i]], 1);
    for (long long i = g; i < E2; i += gs) tick2[i] = atomicAdd(&degu[t2[i]], 1);
}

// ---------------------------------------------------------------------------
// K2: per-1024-chunk sums for both arrays (blocks [0,nbu) user, rest poi)
// ---------------------------------------------------------------------------
__global__ __launch_bounds__(256) void scan_sums_k(
        const int* __restrict__ deg_u, int n_u, int* __restrict__ bs_u, int nbu,
        const int* __restrict__ deg_p, int n_p, int* __restrict__ bs_p) {
    __shared__ int wsum[4];
    const int* deg; int n; int* bs; int bb;
    if (blockIdx.x < (unsigned)nbu) { deg = deg_u; n = n_u; bs = bs_u; bb = blockIdx.x; }
    else { deg = deg_p; n = n_p; bs = bs_p; bb = blockIdx.x - nbu; }
    int base = bb * 1024 + threadIdx.x * 4;
    int s = 0;
#pragma unroll
    for (int l = 0; l < 4; l++) { int i = base + l; s += (i < n) ? deg[i] : 0; }
    int isc = wave_incl_scan(s);
    int lane = threadIdx.x & 63, wid = threadIdx.x >> 6;
    if (lane == 63) wsum[wid] = isc;
    __syncthreads();
    if (threadIdx.x == 0) bs[bb] = wsum[0] + wsum[1] + wsum[2] + wsum[3];
}

// ---------------------------------------------------------------------------
// K3: block 0 = exclusive-scan block sums (wave0 user, wave1 poi);
//     blocks 1..32 = pack 4 weight matrices into MFMA B-fragment order.
// P[w][(kk*8+n0)*64+lane][j] = bf16(W[kk*32+(lane>>4)*8+j][n0*16+(lane&15)])
// ---------------------------------------------------------------------------
__global__ __launch_bounds__(256) void mid_k(int* __restrict__ bs_u, int nbu,
                                             int* __restrict__ bs_p, int nbp,
                                             const float* __restrict__ W0,
                                             const float* __restrict__ W1,
                                             const float* __restrict__ W2,
                                             const float* __restrict__ W3,
                                             ushort* __restrict__ P) {
    if (blockIdx.x == 0) {
        if (threadIdx.x < 128) {
            int lane = threadIdx.x & 63;
            int w = threadIdx.x >> 6;
            int* bs = w ? bs_p : bs_u;
            int nb = w ? nbp : nbu;
            int carry = 0;
            for (int r = 0; r * 64 < nb; r++) {
                int i = r * 64 + lane;
                int v = (i < nb) ? bs[i] : 0;
                int isc = wave_incl_scan(v);
                if (i < nb) bs[i] = isc - v + carry;
                carry += __shfl(isc, 63, 64);
            }
        }
        return;
    }
    int t = (blockIdx.x - 1) * 256 + threadIdx.x;
    if (t >= 4 * 2048) return;
    int w = t >> 11, r = t & 2047;
    int lane = r & 63, fi = r >> 6;
    int kk = fi >> 3, n0 = fi & 7;
    const float* W = (w == 0) ? W0 : (w == 1) ? W1 : (w == 2) ? W2 : W3;
    int col = n0 * 16 + (lane & 15);
    int kb = kk * 32 + (lane >> 4) * 8;
    bf16x8 v;
#pragma unroll
    for (int j = 0; j < 8; j++) v[j] = (short)f2bf(W[(kb + j) * D + col]);
    *(bf16x8*)&P[(long long)t * 8] = v;
}

// ---------------------------------------------------------------------------
// K4: apply block offsets -> start[] (no cursor needed; tickets precomputed)
// ---------------------------------------------------------------------------
__global__ __launch_bounds__(256) void scan_apply_k(
        const int* __restrict__ deg_u, int n_u, const int* __restrict__ bs_u,
        int* __restrict__ start_u, int nbu,
        const int* __restrict__ deg_p, int n_p, const int* __restrict__ bs_p,
        int* __restrict__ start_p) {
    __shared__ int wsum[4];
    const int* deg; int n; const int* bs; int* start; int bb;
    if (blockIdx.x < (unsigned)nbu) { deg = deg_u; n = n_u; bs = bs_u; start = start_u; bb = blockIdx.x; }
    else { deg = deg_p; n = n_p; bs = bs_p; start = start_p; bb = blockIdx.x - nbu; }
    int base = bb * 1024 + threadIdx.x * 4;
    int v[4]; int s = 0;
#pragma unroll
    for (int l = 0; l < 4; l++) { int i = base + l; v[l] = (i < n) ? deg[i] : 0; s += v[l]; }
    int isc = wave_incl_scan(s);
    int lane = threadIdx.x & 63, wid = threadIdx.x >> 6;
    if (lane == 63) wsum[wid] = isc;
    __syncthreads();
    int woff = 0;
#pragma unroll
    for (int k = 0; k < 4; k++) if (k < wid) woff += wsum[k];
    int run = isc - s + woff + bs[bb];
#pragma unroll
    for (int l = 0; l < 4; l++) {
        int i = base + l;
        if (i < n) { start[i] = run; run += v[l]; }
    }
}

// ---------------------------------------------------------------------------
// K5: atomic-free CSR permute, both edge types in one launch.
// perm[start[t] + tick[i]] = src[i]  (nontemporal scattered 4B store)
// ---------------------------------------------------------------------------
__global__ __launch_bounds__(256) void permute_k(
        const int* __restrict__ esA, const int* __restrict__ etA,
        const int* __restrict__ tkA, const int* __restrict__ stA,
        int* __restrict__ pmA, int EA,
        const int* __restrict__ esB, const int* __restrict__ etB,
        const int* __restrict__ tkB, const int* __restrict__ stB,
        int* __restrict__ pmB, int EB) {
    int total = EA + EB;
    int gs = gridDim.x * 256;
    for (int i = blockIdx.x * 256 + threadIdx.x; i < total; i += gs) {
        if (i < EA) {
            int t = etA[i];
            __builtin_nontemporal_store(esA[i], &pmA[stA[t] + tkA[i]]);
        } else {
            int j = i - EA;
            int t = etB[j];
            __builtin_nontemporal_store(esB[j], &pmB[stB[t] + tkB[j]]);
        }
    }
}

// ---------------------------------------------------------------------------
// K6: fused gather-mean (both target sets), one wave per target.
// Writes bf16 agg into the FIRST 256B of each 512B output row of d_out.
// ---------------------------------------------------------------------------
__global__ __launch_bounds__(256) void gather_k(
        const ushort* __restrict__ xb_poi, const int* __restrict__ perm_u,
        const int* __restrict__ start_u, const int* __restrict__ deg_u,
        uint* __restrict__ out_u, int n_user,
        const ushort* __restrict__ xb_user, const int* __restrict__ perm_p,
        const int* __restrict__ start_p, const int* __restrict__ deg_p,
        uint* __restrict__ out_p, int n_poi) {
    int gw = (blockIdx.x * 256 + threadIdx.x) >> 6;
    int lane = threadIdx.x & 63;
    const ushort* xb; const int* perm; const int* start; const int* deg; uint* out; int t;
    if (gw < n_user) { xb = xb_poi; perm = perm_u; start = start_u; deg = deg_u; out = out_u; t = gw; }
    else {
        t = gw - n_user;
        if (t >= n_poi) return;
        xb = xb_user; perm = perm_p; start = start_p; deg = deg_p; out = out_p;
    }
    const uint* x2 = (const uint*)xb;
    int s0 = start[t], dg = deg[t];
    float ax = 0.f, ay = 0.f;
    int j = 0;
    for (; j + 4 <= dg; j += 4) {
        int sa = perm[s0 + j], sb = perm[s0 + j + 1];
        int sc = perm[s0 + j + 2], sd = perm[s0 + j + 3];
        uint va = x2[sa * 64 + lane], vb = x2[sb * 64 + lane];
        uint vc = x2[sc * 64 + lane], vd = x2[sd * 64 + lane];
        ax += (__uint_as_float(va << 16) + __uint_as_float(vb << 16)) +
              (__uint_as_float(vc << 16) + __uint_as_float(vd << 16));
        ay += (__uint_as_float(va & 0xffff0000u) + __uint_as_float(vb & 0xffff0000u)) +
              (__uint_as_float(vc & 0xffff0000u) + __uint_as_float(vd & 0xffff0000u));
    }
    for (; j < dg; j++) {
        int s = perm[s0 + j];
        uint v = x2[s * 64 + lane];
        ax += __uint_as_float(v << 16);
        ay += __uint_as_float(v & 0xffff0000u);
    }
    float scl = 1.0f / fmaxf((float)dg, 1.0f);
    uint o = ((uint)f2bf(ay * scl) << 16) | (uint)f2bf(ax * scl);
    out[(long long)t * 128 + lane] = o;  // row stride = 128 uints = 512B (f32 row)
}

// ---------------------------------------------------------------------------
// K7: fused dual-GEMM via MFMA (both sides in one launch), no LDS.
//   OUT[r] = relu( Xb[r]@Wt + Agg[r]@Ws )
// Agg is bf16 stored in the first 256B of each 512B OUT row (stride 256 ush).
// Per-wave row ownership: wave reads agg of its own rows before storing them.
// Clamped tail reads may race with other waves' stores — masked, benign.
// ---------------------------------------------------------------------------
__global__ __launch_bounds__(256) void mfma_k(
        const ushort* __restrict__ Xb_u, const ushort* __restrict__ WtP_u,
        const ushort* __restrict__ WsP_u, float* __restrict__ OUT_u, int n_u, int bu,
        const ushort* __restrict__ Xb_p, const ushort* __restrict__ WtP_p,
        const ushort* __restrict__ WsP_p, float* __restrict__ OUT_p, int n_p) {
    const ushort* Xb; const ushort* WtP; const ushort* WsP; float* OUT; int nrows, bbase;
    if (blockIdx.x < (unsigned)bu) { Xb = Xb_u; WtP = WtP_u; WsP = WsP_u; OUT = OUT_u; nrows = n_u; bbase = blockIdx.x; }
    else { Xb = Xb_p; WtP = WtP_p; WsP = WsP_p; OUT = OUT_p; nrows = n_p; bbase = blockIdx.x - bu; }
    const ushort* Agg = (const ushort*)OUT;   // row stride 256 ushorts

    const int tid = threadIdx.x;
    const int lane = tid & 63;
    const int wv = tid >> 6;
    const int waveRow = bbase * 128 + wv * 32;
    const int l15 = lane & 15, lhi = lane >> 4;

    f32x4 acc[2][8];
#pragma unroll
    for (int m = 0; m < 2; m++)
#pragma unroll
        for (int n = 0; n < 8; n++) acc[m][n] = (f32x4){0.f, 0.f, 0.f, 0.f};

#pragma unroll
    for (int p = 0; p < 2; p++) {
        const ushort* Wp = p ? WsP : WtP;
#pragma unroll
        for (int kk = 0; kk < 4; kk++) {
            bf16x8 a[2];
#pragma unroll
            for (int m = 0; m < 2; m++) {
                int r = waveRow + m * 16 + l15;
                if (r > nrows - 1) r = nrows - 1;
                a[m] = p ? *(const bf16x8*)&Agg[(long long)r * 256 + kk * 32 + lhi * 8]
                         : *(const bf16x8*)&Xb[(long long)r * D + kk * 32 + lhi * 8];
            }
#pragma unroll
            for (int n = 0; n < 8; n++) {
                bf16x8 b = *(const bf16x8*)&Wp[(long long)((kk * 8 + n) * 64 + lane) * 8];
#pragma unroll
                for (int m = 0; m < 2; m++)
                    acc[m][n] = __builtin_amdgcn_mfma_f32_16x16x32_bf16(a[m], b, acc[m][n], 0, 0, 0);
            }
        }
    }

#pragma unroll
    for (int m = 0; m < 2; m++)
#pragma unroll
        for (int n = 0; n < 8; n++)
#pragma unroll
            for (int ri = 0; ri < 4; ri++) {
                int r = waveRow + m * 16 + lhi * 4 + ri;
                if (r < nrows)
                    OUT[(long long)r * D + n * 16 + l15] = fmaxf(acc[m][n][ri], 0.f);
            }
}

extern "C" void kernel_launch(void* const* d_in, const int* in_sizes, int n_in,
                              void* d_out, int out_size, void* d_ws, size_t ws_size,
                              hipStream_t stream) {
    const float* x_user    = (const float*)d_in[0];
    const float* x_poi     = (const float*)d_in[1];
    const float* W_u2p_src = (const float*)d_in[2];
    const float* W_u2p_tgt = (const float*)d_in[3];
    const float* W_p2u_src = (const float*)d_in[4];
    const float* W_p2u_tgt = (const float*)d_in[5];
    const int* e_u2p_src   = (const int*)d_in[6];
    const int* e_u2p_tgt   = (const int*)d_in[7];
    const int* e_p2u_src   = (const int*)d_in[8];
    const int* e_p2u_tgt   = (const int*)d_in[9];

    const int n_user = in_sizes[0] / D;   // 100000
    const int n_poi  = in_sizes[1] / D;   // 50000
    const int E1 = in_sizes[6];           // u2p (targets = poi, srcs = user)
    const int E2 = in_sizes[8];           // p2u (targets = user, srcs = poi)

    float* out = (float*)d_out;
    float* out_user = out;
    float* out_poi  = out + (long long)n_user * D;

    const int nb_u = (n_user + 1023) / 1024;
    const int nb_p = (n_poi + 1023) / 1024;

    // ---- workspace layout (~56 MB) ----
    char* w = (char*)d_ws;
    ushort* xb_user = (ushort*)w;  w += (size_t)n_user * D * 2;
    ushort* xb_poi  = (ushort*)w;  w += (size_t)n_poi  * D * 2;
    ushort* Wpack   = (ushort*)w;  w += (size_t)4 * 2048 * 8 * 2;
    int* perm_user  = (int*)w;     w += (size_t)E2 * 4;
    int* perm_poi   = (int*)w;     w += (size_t)E1 * 4;
    int* tick_u2p   = (int*)w;     w += (size_t)E1 * 4;
    int* tick_p2u   = (int*)w;     w += (size_t)E2 * 4;
    int* deg_user   = (int*)w;     w += (size_t)n_user * 4;
    int* deg_poi    = (int*)w;     w += (size_t)n_poi * 4;
    int* start_user = (int*)w;     w += (size_t)n_user * 4;
    int* start_poi  = (int*)w;     w += (size_t)n_poi * 4;
    int* bs_user    = (int*)w;     w += (size_t)nb_u * 4;
    int* bs_poi     = (int*)w;     w += (size_t)nb_p * 4;

    ushort* WtP_user = Wpack + 0 * 2048 * 8;   // W_p2u_tgt
    ushort* WsP_user = Wpack + 1 * 2048 * 8;   // W_p2u_src
    ushort* WtP_poi  = Wpack + 2 * 2048 * 8;   // W_u2p_tgt
    ushort* WsP_poi  = Wpack + 3 * 2048 * 8;   // W_u2p_src

    // 0) zero degrees (deg_user & deg_poi are adjacent)
    hipMemsetAsync(deg_user, 0, sizeof(int) * (size_t)(n_user + n_poi), stream);

    // 1) casts + count-with-ticket
    prep_k<<<2048, 256, 0, stream>>>(x_user, xb_user, (long long)n_user * D / 4,
                                     x_poi, xb_poi, (long long)n_poi * D / 4,
                                     e_u2p_tgt, tick_u2p, deg_poi, E1,
                                     e_p2u_tgt, tick_p2u, deg_user, E2);

    // 2-4) scans + weight pack
    scan_sums_k<<<nb_u + nb_p, 256, 0, stream>>>(deg_user, n_user, bs_user, nb_u,
                                                 deg_poi, n_poi, bs_poi);
    mid_k<<<33, 256, 0, stream>>>(bs_user, nb_u, bs_poi, nb_p,
                                  W_p2u_tgt, W_p2u_src, W_u2p_tgt, W_u2p_src, Wpack);
    scan_apply_k<<<nb_u + nb_p, 256, 0, stream>>>(deg_user, n_user, bs_user, start_user, nb_u,
                                                  deg_poi, n_poi, bs_poi, start_poi);

    // 5) atomic-free CSR permute (both types)
    permute_k<<<2048, 256, 0, stream>>>(e_u2p_src, e_u2p_tgt, tick_u2p, start_poi, perm_poi, E1,
                                        e_p2u_src, e_p2u_tgt, tick_p2u, start_user, perm_user, E2);

    // 6) fused gather-mean, bf16 agg into d_out rows
    gather_k<<<(n_user + n_poi + 3) / 4, 256, 0, stream>>>(
        xb_poi, perm_user, start_user, deg_user, (uint*)out_user, n_user,
        xb_user, perm_poi, start_poi, deg_poi, (uint*)out_poi, n_poi);

    // 7) fused dual MFMA GEMM + relu, in place on d_out
    int bu = (n_user + 127) / 128, bp = (n_poi + 127) / 128;
    mfma_k<<<bu + bp, 256, 0, stream>>>(xb_user, WtP_user, WsP_user, out_user, n_user, bu,
                                        xb_poi, WtP_poi, WsP_poi, out_poi, n_poi);
}

// Round 6
// 360.311 us; speedup vs baseline: 3.4966x; 1.2277x over previous
//
#include <hip/hip_runtime.h>
#include <hip/hip_bf16.h>

#define D 128
#define CHUNK 4096          // edges per chunk in hist/binsort
#define BINSZ 128           // targets per bin

typedef __attribute__((ext_vector_type(8))) short bf16x8;  // 8 bf16 = 4 VGPRs
typedef __attribute__((ext_vector_type(4))) float f32x4;

__device__ __forceinline__ ushort f2bf(float f) {
    uint u = __float_as_uint(f);
    u += 0x7fffu + ((u >> 16) & 1u);   // RNE
    return (ushort)(u >> 16);
}

__device__ __forceinline__ int wave_incl_scan(int v) {
    int lane = threadIdx.x & 63;
#pragma unroll
    for (int off = 1; off < 64; off <<= 1) {
        int n = __shfl_up(v, off, 64);
        if (lane >= off) v += n;
    }
    return v;
}

// ---------------------------------------------------------------------------
// K1: pure streaming cast f32 -> bf16 for both node sets
// ---------------------------------------------------------------------------
__global__ __launch_bounds__(256) void cast_k(
        const float* __restrict__ xu, ushort* __restrict__ xbu, long long n4u,
        const float* __restrict__ xp, ushort* __restrict__ xbp, long long n4p) {
    long long g = (long long)blockIdx.x * 256 + threadIdx.x;
    long long gs = (long long)gridDim.x * 256;
    for (long long i = g; i < n4u; i += gs) {
        float4 v = ((const float4*)xu)[i];
        ushort4 o = {f2bf(v.x), f2bf(v.y), f2bf(v.z), f2bf(v.w)};
        ((ushort4*)xbu)[i] = o;
    }
    for (long long i = g; i < n4p; i += gs) {
        float4 v = ((const float4*)xp)[i];
        ushort4 o = {f2bf(v.x), f2bf(v.y), f2bf(v.z), f2bf(v.w)};
        ((ushort4*)xbp)[i] = o;
    }
}

// ---------------------------------------------------------------------------
// K2: per-chunk LDS histogram over bins -> cnt[bin][chunk]
// Blocks [0,CBu): user-target edges (p2u); [CBu,CBu+CBp): poi-target (u2p).
// ---------------------------------------------------------------------------
__global__ __launch_bounds__(256) void hist_k(
        const int* __restrict__ etU, int EU, int* __restrict__ cntU, int NBu, int CBu,
        const int* __restrict__ etP, int EP, int* __restrict__ cntP, int NBp, int CBp) {
    __shared__ int h[800];
    const int* et; int E; int* cnt; int NB, CB, c;
    if (blockIdx.x < (unsigned)CBu) { et = etU; E = EU; cnt = cntU; NB = NBu; CB = CBu; c = blockIdx.x; }
    else { et = etP; E = EP; cnt = cntP; NB = NBp; CB = CBp; c = blockIdx.x - CBu; }
    for (int i = threadIdx.x; i < NB; i += 256) h[i] = 0;
    __syncthreads();
    int lo = c * CHUNK, hi = min(lo + CHUNK, E);
    for (int i = lo + threadIdx.x; i < hi; i += 256) atomicAdd(&h[et[i] >> 7], 1);
    __syncthreads();
    for (int i = threadIdx.x; i < NB; i += 256) cnt[(long long)i * CB + c] = h[i];
}

// ---------------------------------------------------------------------------
// K3: one wave per bin: exclusive-scan cnt[bin][*] in place; total -> tot[bin]
// ---------------------------------------------------------------------------
__global__ __launch_bounds__(256) void binscan_k(
        int* __restrict__ cntU, int* __restrict__ totU, int NBu, int CBu,
        int* __restrict__ cntP, int* __restrict__ totP, int NBp, int CBp) {
    int gw = (blockIdx.x * 256 + threadIdx.x) >> 6;
    int lane = threadIdx.x & 63;
    int* cnt; int* tot; int CB, bin;
    if (gw < NBu) { cnt = cntU; tot = totU; CB = CBu; bin = gw; }
    else {
        bin = gw - NBu;
        if (bin >= NBp) return;
        cnt = cntP; tot = totP; CB = CBp;
    }
    int* row = cnt + (long long)bin * CB;
    int carry = 0;
    for (int r = 0; r * 64 < CB; r++) {
        int i = r * 64 + lane;
        int v = (i < CB) ? row[i] : 0;
        int isc = wave_incl_scan(v);
        if (i < CB) row[i] = isc - v + carry;
        carry += __shfl(isc, 63, 64);
    }
    if (lane == 0) tot[bin] = carry;
}

// ---------------------------------------------------------------------------
// K4: block 0 = exclusive-scan bin totals -> binStart (wave0 user, wave1 poi);
//     blocks 1..32 = pack 4 weight matrices into MFMA B-fragment order.
// ---------------------------------------------------------------------------
__global__ __launch_bounds__(256) void mid_k(
        const int* __restrict__ totU, int* __restrict__ bstU, int NBu,
        const int* __restrict__ totP, int* __restrict__ bstP, int NBp,
        const float* __restrict__ W0, const float* __restrict__ W1,
        const float* __restrict__ W2, const float* __restrict__ W3,
        ushort* __restrict__ P) {
    if (blockIdx.x == 0) {
        if (threadIdx.x < 128) {
            int lane = threadIdx.x & 63;
            int w = threadIdx.x >> 6;
            const int* tot = w ? totP : totU;
            int* bst = w ? bstP : bstU;
            int nb = w ? NBp : NBu;
            int carry = 0;
            for (int r = 0; r * 64 < nb; r++) {
                int i = r * 64 + lane;
                int v = (i < nb) ? tot[i] : 0;
                int isc = wave_incl_scan(v);
                if (i < nb) bst[i] = isc - v + carry;
                carry += __shfl(isc, 63, 64);
            }
        }
        return;
    }
    int t = (blockIdx.x - 1) * 256 + threadIdx.x;
    if (t >= 4 * 2048) return;
    int w = t >> 11, r = t & 2047;
    int lane = r & 63, fi = r >> 6;
    int kk = fi >> 3, n0 = fi & 7;
    const float* W = (w == 0) ? W0 : (w == 1) ? W1 : (w == 2) ? W2 : W3;
    int col = n0 * 16 + (lane & 15);
    int kb = kk * 32 + (lane >> 4) * 8;
    bf16x8 v;
#pragma unroll
    for (int j = 0; j < 8; j++) v[j] = (short)f2bf(W[(kb + j) * D + col]);
    *(bf16x8*)&P[(long long)t * 8] = v;
}

// ---------------------------------------------------------------------------
// K5: bin-sort edges. LDS cursors = binStart[bin] + cnt[bin][chunk]; write
// packed (local_tgt<<17 | src) into the bin's contiguous region.
// ---------------------------------------------------------------------------
__global__ __launch_bounds__(256) void binsort_k(
        const int* __restrict__ esU, const int* __restrict__ etU, int EU,
        const int* __restrict__ cntU, const int* __restrict__ bstU,
        int* __restrict__ binU, int NBu, int CBu,
        const int* __restrict__ esP, const int* __restrict__ etP, int EP,
        const int* __restrict__ cntP, const int* __restrict__ bstP,
        int* __restrict__ binP, int NBp, int CBp) {
    __shared__ int cur[800];
    const int* es; const int* et; int E; const int* cnt; const int* bst;
    int* bnd; int NB, CB, c;
    if (blockIdx.x < (unsigned)CBu) {
        es = esU; et = etU; E = EU; cnt = cntU; bst = bstU; bnd = binU;
        NB = NBu; CB = CBu; c = blockIdx.x;
    } else {
        es = esP; et = etP; E = EP; cnt = cntP; bst = bstP; bnd = binP;
        NB = NBp; CB = CBp; c = blockIdx.x - CBu;
    }
    for (int i = threadIdx.x; i < NB; i += 256)
        cur[i] = bst[i] + cnt[(long long)i * CB + c];
    __syncthreads();
    int lo = c * CHUNK, hi = min(lo + CHUNK, E);
    for (int i = lo + threadIdx.x; i < hi; i += 256) {
        int t = et[i];
        int s = es[i];
        int pos = atomicAdd(&cur[t >> 7], 1);
        bnd[pos] = ((t & 127) << 17) | s;
    }
}

// ---------------------------------------------------------------------------
// K6: per-bin exact CSR: LDS 128-counter histogram -> LDS scan -> coalesced
// deg/start writes + within-bin perm scatter (contiguous region).
// ---------------------------------------------------------------------------
__global__ __launch_bounds__(256) void csr_k(
        const int* __restrict__ binU, const int* __restrict__ bstU,
        const int* __restrict__ totU, int NBu,
        int* __restrict__ degU, int* __restrict__ startU, int* __restrict__ permU, int n_u,
        const int* __restrict__ binP, const int* __restrict__ bstP,
        const int* __restrict__ totP, int NBp,
        int* __restrict__ degP, int* __restrict__ startP, int* __restrict__ permP, int n_p) {
    __shared__ int h[128];
    __shared__ int base[128];
    __shared__ int cur[128];
    const int* bnd; const int* bst; const int* tot;
    int* deg; int* start; int* perm; int n, bin;
    if (blockIdx.x < (unsigned)NBu) {
        bnd = binU; bst = bstU; tot = totU; deg = degU; start = startU; perm = permU;
        n = n_u; bin = blockIdx.x;
    } else {
        bin = blockIdx.x - NBu;
        bnd = binP; bst = bstP; tot = totP; deg = degP; start = startP; perm = permP;
        n = n_p;
    }
    const int tid = threadIdx.x;
    int s0 = bst[bin], cnt = tot[bin];
    if (tid < 128) h[tid] = 0;
    __syncthreads();
    for (int i = s0 + tid; i < s0 + cnt; i += 256) atomicAdd(&h[bnd[i] >> 17], 1);
    __syncthreads();
    if (tid < 64) {
        int carry = 0;
#pragma unroll
        for (int r = 0; r < 2; r++) {
            int i = r * 64 + tid;
            int v = h[i];
            int isc = wave_incl_scan(v);
            base[i] = isc - v + carry;
            carry += __shfl(isc, 63, 64);
        }
    }
    __syncthreads();
    int t0 = bin << 7;
    if (tid < 128) {
        int t = t0 + tid;
        if (t < n) { deg[t] = h[tid]; start[t] = s0 + base[tid]; }
        cur[tid] = s0 + base[tid];
    }
    __syncthreads();
    for (int i = s0 + tid; i < s0 + cnt; i += 256) {
        int v = bnd[i];
        int pos = atomicAdd(&cur[v >> 17], 1);
        perm[pos] = v & 0x1FFFF;
    }
}

// ---------------------------------------------------------------------------
// K7: fused gather-mean (both target sets), one wave per target.
// Writes bf16 agg into the FIRST 256B of each 512B output row of d_out.
// ---------------------------------------------------------------------------
__global__ __launch_bounds__(256) void gather_k(
        const ushort* __restrict__ xb_poi, const int* __restrict__ perm_u,
        const int* __restrict__ start_u, const int* __restrict__ deg_u,
        uint* __restrict__ out_u, int n_user,
        const ushort* __restrict__ xb_user, const int* __restrict__ perm_p,
        const int* __restrict__ start_p, const int* __restrict__ deg_p,
        uint* __restrict__ out_p, int n_poi) {
    int gw = (blockIdx.x * 256 + threadIdx.x) >> 6;
    int lane = threadIdx.x & 63;
    const ushort* xb; const int* perm; const int* start; const int* deg; uint* out; int t;
    if (gw < n_user) { xb = xb_poi; perm = perm_u; start = start_u; deg = deg_u; out = out_u; t = gw; }
    else {
        t = gw - n_user;
        if (t >= n_poi) return;
        xb = xb_user; perm = perm_p; start = start_p; deg = deg_p; out = out_p;
    }
    const uint* x2 = (const uint*)xb;
    int s0 = start[t], dg = deg[t];
    float ax = 0.f, ay = 0.f;
    int j = 0;
    for (; j + 4 <= dg; j += 4) {
        int sa = perm[s0 + j], sb = perm[s0 + j + 1];
        int sc = perm[s0 + j + 2], sd = perm[s0 + j + 3];
        uint va = x2[sa * 64 + lane], vb = x2[sb * 64 + lane];
        uint vc = x2[sc * 64 + lane], vd = x2[sd * 64 + lane];
        ax += (__uint_as_float(va << 16) + __uint_as_float(vb << 16)) +
              (__uint_as_float(vc << 16) + __uint_as_float(vd << 16));
        ay += (__uint_as_float(va & 0xffff0000u) + __uint_as_float(vb & 0xffff0000u)) +
              (__uint_as_float(vc & 0xffff0000u) + __uint_as_float(vd & 0xffff0000u));
    }
    for (; j < dg; j++) {
        int s = perm[s0 + j];
        uint v = x2[s * 64 + lane];
        ax += __uint_as_float(v << 16);
        ay += __uint_as_float(v & 0xffff0000u);
    }
    float scl = 1.0f / fmaxf((float)dg, 1.0f);
    uint o = ((uint)f2bf(ay * scl) << 16) | (uint)f2bf(ax * scl);
    out[(long long)t * 128 + lane] = o;  // row stride = 128 uints = 512B
}

// ---------------------------------------------------------------------------
// K8: fused dual-GEMM via MFMA (both sides in one launch), no LDS.
//   OUT[r] = relu( Xb[r]@Wt + Agg[r]@Ws )
// ---------------------------------------------------------------------------
__global__ __launch_bounds__(256) void mfma_k(
        const ushort* __restrict__ Xb_u, const ushort* __restrict__ WtP_u,
        const ushort* __restrict__ WsP_u, float* __restrict__ OUT_u, int n_u, int bu,
        const ushort* __restrict__ Xb_p, const ushort* __restrict__ WtP_p,
        const ushort* __restrict__ WsP_p, float* __restrict__ OUT_p, int n_p) {
    const ushort* Xb; const ushort* WtP; const ushort* WsP; float* OUT; int nrows, bbase;
    if (blockIdx.x < (unsigned)bu) { Xb = Xb_u; WtP = WtP_u; WsP = WsP_u; OUT = OUT_u; nrows = n_u; bbase = blockIdx.x; }
    else { Xb = Xb_p; WtP = WtP_p; WsP = WsP_p; OUT = OUT_p; nrows = n_p; bbase = blockIdx.x - bu; }
    const ushort* Agg = (const ushort*)OUT;   // row stride 256 ushorts

    const int tid = threadIdx.x;
    const int lane = tid & 63;
    const int wv = tid >> 6;
    const int waveRow = bbase * 128 + wv * 32;
    const int l15 = lane & 15, lhi = lane >> 4;

    f32x4 acc[2][8];
#pragma unroll
    for (int m = 0; m < 2; m++)
#pragma unroll
        for (int n = 0; n < 8; n++) acc[m][n] = (f32x4){0.f, 0.f, 0.f, 0.f};

#pragma unroll
    for (int p = 0; p < 2; p++) {
        const ushort* Wp = p ? WsP : WtP;
#pragma unroll
        for (int kk = 0; kk < 4; kk++) {
            bf16x8 a[2];
#pragma unroll
            for (int m = 0; m < 2; m++) {
                int r = waveRow + m * 16 + l15;
                if (r > nrows - 1) r = nrows - 1;
                a[m] = p ? *(const bf16x8*)&Agg[(long long)r * 256 + kk * 32 + lhi * 8]
                         : *(const bf16x8*)&Xb[(long long)r * D + kk * 32 + lhi * 8];
            }
#pragma unroll
            for (int n = 0; n < 8; n++) {
                bf16x8 b = *(const bf16x8*)&Wp[(long long)((kk * 8 + n) * 64 + lane) * 8];
#pragma unroll
                for (int m = 0; m < 2; m++)
                    acc[m][n] = __builtin_amdgcn_mfma_f32_16x16x32_bf16(a[m], b, acc[m][n], 0, 0, 0);
            }
        }
    }

#pragma unroll
    for (int m = 0; m < 2; m++)
#pragma unroll
        for (int n = 0; n < 8; n++)
#pragma unroll
            for (int ri = 0; ri < 4; ri++) {
                int r = waveRow + m * 16 + lhi * 4 + ri;
                if (r < nrows)
                    OUT[(long long)r * D + n * 16 + l15] = fmaxf(acc[m][n][ri], 0.f);
            }
}

extern "C" void kernel_launch(void* const* d_in, const int* in_sizes, int n_in,
                              void* d_out, int out_size, void* d_ws, size_t ws_size,
                              hipStream_t stream) {
    const float* x_user    = (const float*)d_in[0];
    const float* x_poi     = (const float*)d_in[1];
    const float* W_u2p_src = (const float*)d_in[2];
    const float* W_u2p_tgt = (const float*)d_in[3];
    const float* W_p2u_src = (const float*)d_in[4];
    const float* W_p2u_tgt = (const float*)d_in[5];
    const int* e_u2p_src   = (const int*)d_in[6];
    const int* e_u2p_tgt   = (const int*)d_in[7];
    const int* e_p2u_src   = (const int*)d_in[8];
    const int* e_p2u_tgt   = (const int*)d_in[9];

    const int n_user = in_sizes[0] / D;   // 100000
    const int n_poi  = in_sizes[1] / D;   // 50000
    const int E1 = in_sizes[6];           // u2p (targets = poi, srcs = user)
    const int E2 = in_sizes[8];           // p2u (targets = user, srcs = poi)

    float* out = (float*)d_out;
    float* out_user = out;
    float* out_poi  = out + (long long)n_user * D;

    const int NBu = (n_user + BINSZ - 1) / BINSZ;   // 782
    const int NBp = (n_poi + BINSZ - 1) / BINSZ;    // 391
    const int CBu = (E2 + CHUNK - 1) / CHUNK;       // chunks, user-target edges
    const int CBp = (E1 + CHUNK - 1) / CHUNK;

    // ---- workspace layout (~57 MB) ----
    char* w = (char*)d_ws;
    ushort* xb_user = (ushort*)w;  w += (size_t)n_user * D * 2;
    ushort* xb_poi  = (ushort*)w;  w += (size_t)n_poi  * D * 2;
    ushort* Wpack   = (ushort*)w;  w += (size_t)4 * 2048 * 8 * 2;
    int* binU       = (int*)w;     w += (size_t)E2 * 4;
    int* binP       = (int*)w;     w += (size_t)E1 * 4;
    int* perm_user  = (int*)w;     w += (size_t)E2 * 4;
    int* perm_poi   = (int*)w;     w += (size_t)E1 * 4;
    int* cntU       = (int*)w;     w += (size_t)NBu * CBu * 4;
    int* cntP       = (int*)w;     w += (size_t)NBp * CBp * 4;
    int* totU       = (int*)w;     w += (size_t)NBu * 4;
    int* totP       = (int*)w;     w += (size_t)NBp * 4;
    int* bstU       = (int*)w;     w += (size_t)NBu * 4;
    int* bstP       = (int*)w;     w += (size_t)NBp * 4;
    int* deg_user   = (int*)w;     w += (size_t)n_user * 4;
    int* deg_poi    = (int*)w;     w += (size_t)n_poi * 4;
    int* start_user = (int*)w;     w += (size_t)n_user * 4;
    int* start_poi  = (int*)w;     w += (size_t)n_poi * 4;

    ushort* WtP_user = Wpack + 0 * 2048 * 8;   // W_p2u_tgt
    ushort* WsP_user = Wpack + 1 * 2048 * 8;   // W_p2u_src
    ushort* WtP_poi  = Wpack + 2 * 2048 * 8;   // W_u2p_tgt
    ushort* WsP_poi  = Wpack + 3 * 2048 * 8;   // W_u2p_src

    // 1) streaming cast
    cast_k<<<2048, 256, 0, stream>>>(x_user, xb_user, (long long)n_user * D / 4,
                                     x_poi, xb_poi, (long long)n_poi * D / 4);

    // 2) per-chunk bin histograms (both edge types)
    hist_k<<<CBu + CBp, 256, 0, stream>>>(e_p2u_tgt, E2, cntU, NBu, CBu,
                                          e_u2p_tgt, E1, cntP, NBp, CBp);

    // 3) per-bin chunk scans
    {
        int nw = NBu + NBp;
        binscan_k<<<(nw + 3) / 4, 256, 0, stream>>>(cntU, totU, NBu, CBu,
                                                    cntP, totP, NBp, CBp);
    }

    // 4) bin-start scan + weight pack
    mid_k<<<33, 256, 0, stream>>>(totU, bstU, NBu, totP, bstP, NBp,
                                  W_p2u_tgt, W_p2u_src, W_u2p_tgt, W_u2p_src, Wpack);

    // 5) bin-sort edges (packed local_tgt|src)
    binsort_k<<<CBu + CBp, 256, 0, stream>>>(
        e_p2u_src, e_p2u_tgt, E2, cntU, bstU, binU, NBu, CBu,
        e_u2p_src, e_u2p_tgt, E1, cntP, bstP, binP, NBp, CBp);

    // 6) per-bin exact CSR (deg/start/perm), all LDS atomics
    csr_k<<<NBu + NBp, 256, 0, stream>>>(
        binU, bstU, totU, NBu, deg_user, start_user, perm_user, n_user,
        binP, bstP, totP, NBp, deg_poi, start_poi, perm_poi, n_poi);

    // 7) fused gather-mean, bf16 agg into d_out rows
    gather_k<<<(n_user + n_poi + 3) / 4, 256, 0, stream>>>(
        xb_poi, perm_user, start_user, deg_user, (uint*)out_user, n_user,
        xb_user, perm_poi, start_poi, deg_poi, (uint*)out_poi, n_poi);

    // 8) fused dual MFMA GEMM + relu, in place on d_out
    int bu = (n_user + 127) / 128, bp = (n_poi + 127) / 128;
    mfma_k<<<bu + bp, 256, 0, stream>>>(xb_user, WtP_user, WsP_user, out_user, n_user, bu,
                                        xb_poi, WtP_poi, WsP_poi, out_poi, n_poi);
}

// Round 7
// 339.195 us; speedup vs baseline: 3.7143x; 1.0623x over previous
//
#include <hip/hip_runtime.h>
#include <hip/hip_bf16.h>

#define D 128
#define CHUNK 4096          // edges per chunk in hist/binsort
#define BINSZ 128           // targets per bin
#define CAP 4096            // LDS edge capacity per bin (spill beyond)

typedef __attribute__((ext_vector_type(8))) short bf16x8;  // 8 bf16 = 4 VGPRs
typedef __attribute__((ext_vector_type(4))) float f32x4;

__device__ __forceinline__ ushort f2bf(float f) {
    uint u = __float_as_uint(f);
    u += 0x7fffu + ((u >> 16) & 1u);   // RNE
    return (ushort)(u >> 16);
}

__device__ __forceinline__ int wave_incl_scan(int v) {
    int lane = threadIdx.x & 63;
#pragma unroll
    for (int off = 1; off < 64; off <<= 1) {
        int n = __shfl_up(v, off, 64);
        if (lane >= off) v += n;
    }
    return v;
}

// ---------------------------------------------------------------------------
// K1: pure streaming cast f32 -> bf16 for both node sets
// ---------------------------------------------------------------------------
__global__ __launch_bounds__(256) void cast_k(
        const float* __restrict__ xu, ushort* __restrict__ xbu, long long n4u,
        const float* __restrict__ xp, ushort* __restrict__ xbp, long long n4p) {
    long long g = (long long)blockIdx.x * 256 + threadIdx.x;
    long long gs = (long long)gridDim.x * 256;
    for (long long i = g; i < n4u; i += gs) {
        float4 v = ((const float4*)xu)[i];
        ushort4 o = {f2bf(v.x), f2bf(v.y), f2bf(v.z), f2bf(v.w)};
        ((ushort4*)xbu)[i] = o;
    }
    for (long long i = g; i < n4p; i += gs) {
        float4 v = ((const float4*)xp)[i];
        ushort4 o = {f2bf(v.x), f2bf(v.y), f2bf(v.z), f2bf(v.w)};
        ((ushort4*)xbp)[i] = o;
    }
}

// ---------------------------------------------------------------------------
// K2: per-chunk LDS histogram over bins -> cnt[bin][chunk]
// ---------------------------------------------------------------------------
__global__ __launch_bounds__(256) void hist_k(
        const int* __restrict__ etU, int EU, int* __restrict__ cntU, int NBu, int CBu,
        const int* __restrict__ etP, int EP, int* __restrict__ cntP, int NBp, int CBp) {
    __shared__ int h[800];
    const int* et; int E; int* cnt; int NB, CB, c;
    if (blockIdx.x < (unsigned)CBu) { et = etU; E = EU; cnt = cntU; NB = NBu; CB = CBu; c = blockIdx.x; }
    else { et = etP; E = EP; cnt = cntP; NB = NBp; CB = CBp; c = blockIdx.x - CBu; }
    for (int i = threadIdx.x; i < NB; i += 256) h[i] = 0;
    __syncthreads();
    int lo = c * CHUNK, hi = min(lo + CHUNK, E);
    for (int i = lo + threadIdx.x; i < hi; i += 256) atomicAdd(&h[et[i] >> 7], 1);
    __syncthreads();
    for (int i = threadIdx.x; i < NB; i += 256) cnt[(long long)i * CB + c] = h[i];
}

// ---------------------------------------------------------------------------
// K3: one wave per bin: exclusive-scan cnt[bin][*] in place; total -> tot[bin]
// ---------------------------------------------------------------------------
__global__ __launch_bounds__(256) void binscan_k(
        int* __restrict__ cntU, int* __restrict__ totU, int NBu, int CBu,
        int* __restrict__ cntP, int* __restrict__ totP, int NBp, int CBp) {
    int gw = (blockIdx.x * 256 + threadIdx.x) >> 6;
    int lane = threadIdx.x & 63;
    int* cnt; int* tot; int CB, bin;
    if (gw < NBu) { cnt = cntU; tot = totU; CB = CBu; bin = gw; }
    else {
        bin = gw - NBu;
        if (bin >= NBp) return;
        cnt = cntP; tot = totP; CB = CBp;
    }
    int* row = cnt + (long long)bin * CB;
    int carry = 0;
    for (int r = 0; r * 64 < CB; r++) {
        int i = r * 64 + lane;
        int v = (i < CB) ? row[i] : 0;
        int isc = wave_incl_scan(v);
        if (i < CB) row[i] = isc - v + carry;
        carry += __shfl(isc, 63, 64);
    }
    if (lane == 0) tot[bin] = carry;
}

// ---------------------------------------------------------------------------
// K4: block 0 = exclusive-scan bin totals -> binStart (wave0 user, wave1 poi);
//     blocks 1..32 = pack 4 weight matrices into MFMA B-fragment order.
// ---------------------------------------------------------------------------
__global__ __launch_bounds__(256) void mid_k(
        const int* __restrict__ totU, int* __restrict__ bstU, int NBu,
        const int* __restrict__ totP, int* __restrict__ bstP, int NBp,
        const float* __restrict__ W0, const float* __restrict__ W1,
        const float* __restrict__ W2, const float* __restrict__ W3,
        ushort* __restrict__ P) {
    if (blockIdx.x == 0) {
        if (threadIdx.x < 128) {
            int lane = threadIdx.x & 63;
            int w = threadIdx.x >> 6;
            const int* tot = w ? totP : totU;
            int* bst = w ? bstP : bstU;
            int nb = w ? NBp : NBu;
            int carry = 0;
            for (int r = 0; r * 64 < nb; r++) {
                int i = r * 64 + lane;
                int v = (i < nb) ? tot[i] : 0;
                int isc = wave_incl_scan(v);
                if (i < nb) bst[i] = isc - v + carry;
                carry += __shfl(isc, 63, 64);
            }
        }
        return;
    }
    int t = (blockIdx.x - 1) * 256 + threadIdx.x;
    if (t >= 4 * 2048) return;
    int w = t >> 11, r = t & 2047;
    int lane = r & 63, fi = r >> 6;
    int kk = fi >> 3, n0 = fi & 7;
    const float* W = (w == 0) ? W0 : (w == 1) ? W1 : (w == 2) ? W2 : W3;
    int col = n0 * 16 + (lane & 15);
    int kb = kk * 32 + (lane >> 4) * 8;
    bf16x8 v;
#pragma unroll
    for (int j = 0; j < 8; j++) v[j] = (short)f2bf(W[(kb + j) * D + col]);
    *(bf16x8*)&P[(long long)t * 8] = v;
}

// ---------------------------------------------------------------------------
// K5: bin-sort edges. LDS cursors = binStart[bin] + cnt[bin][chunk]; write
// packed (local_tgt<<17 | src) into the bin's contiguous region.
// ---------------------------------------------------------------------------
__global__ __launch_bounds__(256) void binsort_k(
        const int* __restrict__ esU, const int* __restrict__ etU, int EU,
        const int* __restrict__ cntU, const int* __restrict__ bstU,
        int* __restrict__ binU, int NBu, int CBu,
        const int* __restrict__ esP, const int* __restrict__ etP, int EP,
        const int* __restrict__ cntP, const int* __restrict__ bstP,
        int* __restrict__ binP, int NBp, int CBp) {
    __shared__ int cur[800];
    const int* es; const int* et; int E; const int* cnt; const int* bst;
    int* bnd; int NB, CB, c;
    if (blockIdx.x < (unsigned)CBu) {
        es = esU; et = etU; E = EU; cnt = cntU; bst = bstU; bnd = binU;
        NB = NBu; CB = CBu; c = blockIdx.x;
    } else {
        es = esP; et = etP; E = EP; cnt = cntP; bst = bstP; bnd = binP;
        NB = NBp; CB = CBp; c = blockIdx.x - CBu;
    }
    for (int i = threadIdx.x; i < NB; i += 256)
        cur[i] = bst[i] + cnt[(long long)i * CB + c];
    __syncthreads();
    int lo = c * CHUNK, hi = min(lo + CHUNK, E);
    for (int i = lo + threadIdx.x; i < hi; i += 256) {
        int t = et[i];
        int s = es[i];
        int pos = atomicAdd(&cur[t >> 7], 1);
        bnd[pos] = ((t & 127) << 17) | s;
    }
}

// ---------------------------------------------------------------------------
// K6: FUSED per-bin kernel: in-LDS CSR + gather-mean + dual MFMA GEMM + relu.
// 512 threads = 8 waves; bin = 128 targets = the GEMM row-tile.
//   OUT[r] = relu( Xb[r]@Wt + mean_r@Ws )
// ---------------------------------------------------------------------------
__global__ __launch_bounds__(512) void fused_k(
        const int* __restrict__ bndU, const int* __restrict__ bstU,
        const int* __restrict__ totU, int NBu, int* __restrict__ spillU,
        const ushort* __restrict__ gsrcU, const ushort* __restrict__ XbU,
        const ushort* __restrict__ WtPU, const ushort* __restrict__ WsPU,
        float* __restrict__ OUTU, int n_u,
        const int* __restrict__ bndP, const int* __restrict__ bstP,
        const int* __restrict__ totP, int* __restrict__ spillP,
        const ushort* __restrict__ gsrcP, const ushort* __restrict__ XbP,
        const ushort* __restrict__ WtPP, const ushort* __restrict__ WsPP,
        float* __restrict__ OUTP, int n_p) {
    __shared__ int eLds[CAP];             // 16 KB sorted src ids
    __shared__ ushort agg[128][136];      // 34 KB bf16 means (+pad vs bank conflicts)
    __shared__ int h[128], sbase[128], scur[128];

    const int* bnd; const int* bst; const int* tot; int* spill;
    const ushort* gsrc; const ushort* Xb; const ushort* WtP; const ushort* WsP;
    float* OUT; int n, bb;
    if (blockIdx.x < (unsigned)NBu) {
        bnd = bndU; bst = bstU; tot = totU; spill = spillU; gsrc = gsrcU; Xb = XbU;
        WtP = WtPU; WsP = WsPU; OUT = OUTU; n = n_u; bb = blockIdx.x;
    } else {
        bb = blockIdx.x - NBu;
        bnd = bndP; bst = bstP; tot = totP; spill = spillP; gsrc = gsrcP; Xb = XbP;
        WtP = WtPP; WsP = WsPP; OUT = OUTP; n = n_p;
    }
    const int tid = threadIdx.x;
    const int lane = tid & 63;
    const int wv = tid >> 6;              // 0..7
    const int t0 = bb << 7;               // global target base of this bin
    const int s0 = bst[bb];
    const int cnt = tot[bb];

    // --- per-target histogram ---
    if (tid < 128) h[tid] = 0;
    __syncthreads();
    for (int i = s0 + tid; i < s0 + cnt; i += 512)
        atomicAdd(&h[bnd[i] >> 17], 1);
    __syncthreads();
    // --- exact 128-entry exclusive scan (wave 0) ---
    if (tid < 64) {
        int carry = 0;
#pragma unroll
        for (int r = 0; r < 2; r++) {
            int i = r * 64 + tid;
            int v = h[i];
            int isc = wave_incl_scan(v);
            sbase[i] = isc - v + carry;
            carry += __shfl(isc, 63, 64);
        }
    }
    __syncthreads();
    if (tid < 128) scur[tid] = sbase[tid];
    __syncthreads();
    // --- scatter src ids into LDS sorted by target (spill if bin > CAP) ---
    for (int i = s0 + tid; i < s0 + cnt; i += 512) {
        int v = bnd[i];
        int pos = atomicAdd(&scur[v >> 17], 1);
        int src = v & 0x1FFFF;
        if (pos < CAP) eLds[pos] = src;
        else spill[s0 + pos] = src;
    }
    __syncthreads();

    // --- gather-mean: wave wv owns local rows [wv*16, wv*16+16) ---
    const uint* x2 = (const uint*)gsrc;
#pragma unroll 1
    for (int q = 0; q < 16; q++) {
        int lt = wv * 16 + q;
        int b0 = sbase[lt], dg = h[lt];
        float ax = 0.f, ay = 0.f;
        int j = 0;
        for (; j + 4 <= dg; j += 4) {
            int p = b0 + j;
            int sa = (p     < CAP) ? eLds[p]     : spill[s0 + p];
            int sb = (p + 1 < CAP) ? eLds[p + 1] : spill[s0 + p + 1];
            int sc = (p + 2 < CAP) ? eLds[p + 2] : spill[s0 + p + 2];
            int sd = (p + 3 < CAP) ? eLds[p + 3] : spill[s0 + p + 3];
            uint va = x2[sa * 64 + lane], vb = x2[sb * 64 + lane];
            uint vc = x2[sc * 64 + lane], vd = x2[sd * 64 + lane];
            ax += (__uint_as_float(va << 16) + __uint_as_float(vb << 16)) +
                  (__uint_as_float(vc << 16) + __uint_as_float(vd << 16));
            ay += (__uint_as_float(va & 0xffff0000u) + __uint_as_float(vb & 0xffff0000u)) +
                  (__uint_as_float(vc & 0xffff0000u) + __uint_as_float(vd & 0xffff0000u));
        }
        for (; j < dg; j++) {
            int p = b0 + j;
            int s = (p < CAP) ? eLds[p] : spill[s0 + p];
            uint v = x2[s * 64 + lane];
            ax += __uint_as_float(v << 16);
            ay += __uint_as_float(v & 0xffff0000u);
        }
        float scl = 1.0f / fmaxf((float)dg, 1.0f);
        uint o = ((uint)f2bf(ay * scl) << 16) | (uint)f2bf(ax * scl);
        *(uint*)&agg[lt][2 * lane] = o;
    }
    __syncthreads();

    // --- dual GEMM: acc = Xb_rows @ Wt + agg @ Ws ; relu; store ---
    const int l15 = lane & 15, lhi = lane >> 4;
    f32x4 acc[8];
#pragma unroll
    for (int nn = 0; nn < 8; nn++) acc[nn] = (f32x4){0.f, 0.f, 0.f, 0.f};

    int rA = t0 + wv * 16 + l15;
    if (rA > n - 1) rA = n - 1;
#pragma unroll
    for (int kk = 0; kk < 4; kk++) {
        bf16x8 a0 = *(const bf16x8*)&Xb[(long long)rA * D + kk * 32 + lhi * 8];
#pragma unroll
        for (int nn = 0; nn < 8; nn++) {
            bf16x8 b = *(const bf16x8*)&WtP[(long long)((kk * 8 + nn) * 64 + lane) * 8];
            acc[nn] = __builtin_amdgcn_mfma_f32_16x16x32_bf16(a0, b, acc[nn], 0, 0, 0);
        }
    }
    const int rl = wv * 16 + l15;
#pragma unroll
    for (int kk = 0; kk < 4; kk++) {
        bf16x8 a1 = *(const bf16x8*)&agg[rl][kk * 32 + lhi * 8];
#pragma unroll
        for (int nn = 0; nn < 8; nn++) {
            bf16x8 b = *(const bf16x8*)&WsP[(long long)((kk * 8 + nn) * 64 + lane) * 8];
            acc[nn] = __builtin_amdgcn_mfma_f32_16x16x32_bf16(a1, b, acc[nn], 0, 0, 0);
        }
    }

#pragma unroll
    for (int nn = 0; nn < 8; nn++)
#pragma unroll
        for (int ri = 0; ri < 4; ri++) {
            int r = t0 + wv * 16 + lhi * 4 + ri;
            if (r < n)
                OUT[(long long)r * D + nn * 16 + l15] = fmaxf(acc[nn][ri], 0.f);
        }
}

extern "C" void kernel_launch(void* const* d_in, const int* in_sizes, int n_in,
                              void* d_out, int out_size, void* d_ws, size_t ws_size,
                              hipStream_t stream) {
    const float* x_user    = (const float*)d_in[0];
    const float* x_poi     = (const float*)d_in[1];
    const float* W_u2p_src = (const float*)d_in[2];
    const float* W_u2p_tgt = (const float*)d_in[3];
    const float* W_p2u_src = (const float*)d_in[4];
    const float* W_p2u_tgt = (const float*)d_in[5];
    const int* e_u2p_src   = (const int*)d_in[6];
    const int* e_u2p_tgt   = (const int*)d_in[7];
    const int* e_p2u_src   = (const int*)d_in[8];
    const int* e_p2u_tgt   = (const int*)d_in[9];

    const int n_user = in_sizes[0] / D;   // 100000
    const int n_poi  = in_sizes[1] / D;   // 50000
    const int E1 = in_sizes[6];           // u2p (targets = poi, srcs = user)
    const int E2 = in_sizes[8];           // p2u (targets = user, srcs = poi)

    float* out = (float*)d_out;
    float* out_user = out;
    float* out_poi  = out + (long long)n_user * D;

    const int NBu = (n_user + BINSZ - 1) / BINSZ;   // 782
    const int NBp = (n_poi + BINSZ - 1) / BINSZ;    // 391
    const int CBu = (E2 + CHUNK - 1) / CHUNK;
    const int CBp = (E1 + CHUNK - 1) / CHUNK;

    // ---- workspace layout (~56 MB) ----
    char* w = (char*)d_ws;
    ushort* xb_user = (ushort*)w;  w += (size_t)n_user * D * 2;
    ushort* xb_poi  = (ushort*)w;  w += (size_t)n_poi  * D * 2;
    ushort* Wpack   = (ushort*)w;  w += (size_t)4 * 2048 * 8 * 2;
    int* binU       = (int*)w;     w += (size_t)E2 * 4;
    int* binP       = (int*)w;     w += (size_t)E1 * 4;
    int* spillU     = (int*)w;     w += (size_t)E2 * 4;
    int* spillP     = (int*)w;     w += (size_t)E1 * 4;
    int* cntU       = (int*)w;     w += (size_t)NBu * CBu * 4;
    int* cntP       = (int*)w;     w += (size_t)NBp * CBp * 4;
    int* totU       = (int*)w;     w += (size_t)NBu * 4;
    int* totP       = (int*)w;     w += (size_t)NBp * 4;
    int* bstU       = (int*)w;     w += (size_t)NBu * 4;
    int* bstP       = (int*)w;     w += (size_t)NBp * 4;

    ushort* WtP_user = Wpack + 0 * 2048 * 8;   // W_p2u_tgt
    ushort* WsP_user = Wpack + 1 * 2048 * 8;   // W_p2u_src
    ushort* WtP_poi  = Wpack + 2 * 2048 * 8;   // W_u2p_tgt
    ushort* WsP_poi  = Wpack + 3 * 2048 * 8;   // W_u2p_src

    // 1) streaming cast
    cast_k<<<2048, 256, 0, stream>>>(x_user, xb_user, (long long)n_user * D / 4,
                                     x_poi, xb_poi, (long long)n_poi * D / 4);

    // 2) per-chunk bin histograms (both edge types)
    hist_k<<<CBu + CBp, 256, 0, stream>>>(e_p2u_tgt, E2, cntU, NBu, CBu,
                                          e_u2p_tgt, E1, cntP, NBp, CBp);

    // 3) per-bin chunk scans
    binscan_k<<<(NBu + NBp + 3) / 4, 256, 0, stream>>>(cntU, totU, NBu, CBu,
                                                       cntP, totP, NBp, CBp);

    // 4) bin-start scan + weight pack
    mid_k<<<33, 256, 0, stream>>>(totU, bstU, NBu, totP, bstP, NBp,
                                  W_p2u_tgt, W_p2u_src, W_u2p_tgt, W_u2p_src, Wpack);

    // 5) bin-sort edges (packed local_tgt|src)
    binsort_k<<<CBu + CBp, 256, 0, stream>>>(
        e_p2u_src, e_p2u_tgt, E2, cntU, bstU, binU, NBu, CBu,
        e_u2p_src, e_u2p_tgt, E1, cntP, bstP, binP, NBp, CBp);

    // 6) fused per-bin CSR + gather-mean + dual MFMA GEMM + relu
    fused_k<<<NBu + NBp, 512, 0, stream>>>(
        binU, bstU, totU, NBu, spillU, xb_poi, xb_user,
        WtP_user, WsP_user, out_user, n_user,
        binP, bstP, totP, spillP, xb_user, xb_poi,
        WtP_poi, WsP_poi, out_poi, n_poi);
}